// Round 5
// baseline (398.655 us; speedup 1.0000x reference)
//
#include <hip/hip_runtime.h>
#include <hip/hip_bf16.h>
#include <cstdint>
#include <math.h>

// Problem constants
#define SEQ 1024
#define DIM 2560
#define HD 128
#define NH 20
#define NKV 5
#define QKV_OUT 3840
#define GS 128

typedef __bf16 bf16;
typedef __bf16 bf16x4 __attribute__((ext_vector_type(4)));
typedef __bf16 bf16x8 __attribute__((ext_vector_type(8)));
typedef float f32x4 __attribute__((ext_vector_type(4)));

// ---------------------------------------------------------------------------
// 1) per-token activation quant: s = 127/clip(amax,1e-5); q=clip(round(x*s));
//    store q as bf16 (ints <=128 exact in bf16), rs = 1/s
// ---------------------------------------------------------------------------
__global__ __launch_bounds__(256) void quant_kernel(
    const float* __restrict__ x, bf16* __restrict__ act,
    float* __restrict__ rs, int cols) {
  const int row = blockIdx.x;
  const int tid = threadIdx.x;
  const float* xr = x + (size_t)row * cols;
  float m = 0.f;
  for (int i = tid; i < cols; i += 256) m = fmaxf(m, fabsf(xr[i]));
  for (int off = 32; off; off >>= 1) m = fmaxf(m, __shfl_xor(m, off));
  __shared__ float red[4];
  __shared__ float s_bc;
  if ((tid & 63) == 0) red[tid >> 6] = m;
  __syncthreads();
  if (tid == 0) {
    float mm = fmaxf(fmaxf(red[0], red[1]), fmaxf(red[2], red[3]));
    mm = fmaxf(mm, 1e-5f);
    s_bc = 127.f / mm;
    rs[row] = mm / 127.f;
  }
  __syncthreads();
  const float s = s_bc;
  bf16* ar = act + (size_t)row * cols;
  for (int i = tid; i < cols; i += 256) {
    float q = rintf(xr[i] * s);
    q = fminf(fmaxf(q, -128.f), 127.f);
    ar[i] = (bf16)q;
  }
}

// ---------------------------------------------------------------------------
// 2) weight dequant: wdq[o,k] = bf16(w[o,k] * ws[o, k/128])
// ---------------------------------------------------------------------------
__global__ __launch_bounds__(256) void dequant_kernel(
    const float* __restrict__ w, const float* __restrict__ ws,
    bf16* __restrict__ wdq, int K, long total4) {
  long i = (long)blockIdx.x * 256 + threadIdx.x;
  if (i >= total4) return;
  long e = i * 4;
  int row = (int)(e / K);
  int k = (int)(e % K);
  float sc = ws[(size_t)row * (K / GS) + (k / GS)];
  float4 wv = *(const float4*)(w + e);
  bf16x4 o;
  o[0] = (bf16)(wv.x * sc);
  o[1] = (bf16)(wv.y * sc);
  o[2] = (bf16)(wv.z * sc);
  o[3] = (bf16)(wv.w * sc);
  *(bf16x4*)(wdq + e) = o;
}

// ---------------------------------------------------------------------------
// 3) bf16 MFMA GEMM, C[m,n] = (sum_k A[m,k]*B[n,k]) * rs[m]  (m97 structure)
// ---------------------------------------------------------------------------
__device__ __forceinline__ void gload_lds16(const bf16* g, bf16* l) {
  __builtin_amdgcn_global_load_lds(
      (const __attribute__((address_space(1))) void*)g,
      (__attribute__((address_space(3))) void*)l, 16, 0, 0);
}

template <int OUT_BF16>
__global__ __launch_bounds__(256) void gemm_bt(
    const bf16* __restrict__ A, const bf16* __restrict__ B,
    const float* __restrict__ rs, void* __restrict__ C, int N, int K) {
  __shared__ bf16 As[128 * 64];
  __shared__ bf16 Bs[128 * 64];
  const int tid = threadIdx.x;
  const int w = tid >> 6, l = tid & 63;
  const int row0 = blockIdx.y * 128;
  const int col0 = blockIdx.x * 128;
  const int wm = (w >> 1) * 64, wn = (w & 1) * 64;
  const int lcol = l & 15, quad = l >> 4;
  const int sr = l >> 3;
  const int sk = (l & 7) * 8;
  const bf16* Ag = A + (size_t)row0 * K;
  const bf16* Bg = B + (size_t)col0 * K;

  f32x4 acc[4][4] = {};

  for (int k0 = 0; k0 < K; k0 += 64) {
    __syncthreads();
#pragma unroll
    for (int i = 0; i < 4; ++i) {
      int r = i * 32 + w * 8 + sr;
      gload_lds16(Ag + (size_t)r * K + k0 + sk, As + (i * 32 + w * 8) * 64);
    }
#pragma unroll
    for (int i = 0; i < 4; ++i) {
      int r = i * 32 + w * 8 + sr;
      gload_lds16(Bg + (size_t)r * K + k0 + sk, Bs + (i * 32 + w * 8) * 64);
    }
    __syncthreads();
#pragma unroll
    for (int ks = 0; ks < 2; ++ks) {
      const int kk = ks * 32 + quad * 8;
      bf16x8 af[4], bff[4];
#pragma unroll
      for (int mi = 0; mi < 4; ++mi)
        af[mi] = *(const bf16x8*)(As + (wm + mi * 16 + lcol) * 64 + kk);
#pragma unroll
      for (int ni = 0; ni < 4; ++ni)
        bff[ni] = *(const bf16x8*)(Bs + (wn + ni * 16 + lcol) * 64 + kk);
#pragma unroll
      for (int mi = 0; mi < 4; ++mi)
#pragma unroll
        for (int ni = 0; ni < 4; ++ni)
          acc[mi][ni] = __builtin_amdgcn_mfma_f32_16x16x32_bf16(
              af[mi], bff[ni], acc[mi][ni], 0, 0, 0);
    }
  }
#pragma unroll
  for (int mi = 0; mi < 4; ++mi) {
#pragma unroll
    for (int ni = 0; ni < 4; ++ni) {
      int col = col0 + wn + ni * 16 + lcol;
#pragma unroll
      for (int r = 0; r < 4; ++r) {
        int row = row0 + wm + mi * 16 + quad * 4 + r;
        float v = acc[mi][ni][r] * rs[row];
        if (OUT_BF16)
          ((bf16*)C)[(size_t)row * N + col] = (bf16)v;
        else
          ((float*)C)[(size_t)row * N + col] = v;
      }
    }
  }
}

// ---------------------------------------------------------------------------
// 4a) q/k postprocess: rmsnorm + rope; bf16. Qo [t][h][d], Ko [g][key][d]
// ---------------------------------------------------------------------------
__global__ void qk_post(const float* __restrict__ qkv,
                        const float* __restrict__ qw, const float* __restrict__ kw,
                        bf16* __restrict__ Qo, bf16* __restrict__ Ko) {
  const int t = blockIdx.x, h = blockIdx.y, i = threadIdx.x;
  const float* src = (h < NH)
      ? qkv + (size_t)t * QKV_OUT + h * HD
      : qkv + (size_t)t * QKV_OUT + 2560 + (h - NH) * HD;
  float x0 = src[2 * i], x1 = src[2 * i + 1];
  float ss = x0 * x0 + x1 * x1;
  for (int off = 1; off < 64; off <<= 1) ss += __shfl_xor(ss, off);
  float r = rsqrtf(ss * (1.f / 128.f) + 1e-5f);
  const float* wv = (h < NH) ? qw : kw;
  float y0 = x0 * r * wv[2 * i];
  float y1 = x1 * r * wv[2 * i + 1];
  float inv_freq = powf(500000.f, -(float)(2 * i) * (1.f / 128.f));
  float ang = (float)t * inv_freq;
  float sn, cs;
  sincosf(ang, &sn, &cs);
  float o0 = y0 * cs - y1 * sn;
  float o1 = y0 * sn + y1 * cs;
  if (h < NH) {
    bf16* dst = Qo + ((size_t)t * NH + h) * HD + 2 * i;
    dst[0] = (bf16)o0; dst[1] = (bf16)o1;
  } else {
    bf16* dst = Ko + ((size_t)(h - NH) * SEQ + t) * HD + 2 * i;
    dst[0] = (bf16)o0; dst[1] = (bf16)o1;
  }
}

// ---------------------------------------------------------------------------
// 4b) V transpose: qkv fp32 [t][3200+g*128+d] -> Vt bf16 [g][d][t]
// ---------------------------------------------------------------------------
__global__ __launch_bounds__(256) void v_post(const float* __restrict__ qkv,
                                              bf16* __restrict__ Vt) {
  const int t0 = blockIdx.x * 64, g = blockIdx.y;
  const int tid = threadIdx.x;
  __shared__ bf16 Ls[64 * 137];
  {
    const int tl = tid >> 4;
    const int d0 = (tid & 15) * 8;
#pragma unroll
    for (int pass = 0; pass < 4; ++pass) {
      int t = pass * 16 + tl;
      const float* src = qkv + (size_t)(t0 + t) * QKV_OUT + 3200 + g * HD + d0;
      float4 a = *(const float4*)src;
      float4 b = *(const float4*)(src + 4);
      bf16* dst = Ls + t * 137 + d0;
      dst[0] = (bf16)a.x; dst[1] = (bf16)a.y; dst[2] = (bf16)a.z; dst[3] = (bf16)a.w;
      dst[4] = (bf16)b.x; dst[5] = (bf16)b.y; dst[6] = (bf16)b.z; dst[7] = (bf16)b.w;
    }
  }
  __syncthreads();
  {
    const int dl = tid >> 3;
    const int tl0 = (tid & 7) * 8;
#pragma unroll
    for (int pass = 0; pass < 4; ++pass) {
      int d = pass * 32 + dl;
      bf16x8 v;
#pragma unroll
      for (int j = 0; j < 8; ++j) v[j] = Ls[(tl0 + j) * 137 + d];
      *(bf16x8*)(Vt + ((size_t)g * HD + d) * SEQ + t0 + tl0) = v;
    }
  }
}

// ---------------------------------------------------------------------------
// 5) MFMA GQA causal flash attention, LDS-staged, double-buffered.
//    Block = 256 thr (4 waves) per (64-q block, head); wave w owns q-rows
//    [qb*64+w*16, +16). Per 64-key tile: K (64x128) and V^T (128x64) staged
//    into LDS via global_load_lds w16 (coalesced, once per block), all waves
//    compute from ds_reads. P^T B-frag from own S regs (permuted k). No
//    cross-wave combine.
// ---------------------------------------------------------------------------
__global__ __launch_bounds__(256) void attn_mfma(
    const bf16* __restrict__ Qb, const bf16* __restrict__ Kb,
    const bf16* __restrict__ Vt, float* __restrict__ O) {
  const int qb = 15 - (int)blockIdx.x;     // long blocks first
  const int H = blockIdx.y, g = H >> 2;
  const int tid = threadIdx.x;
  const int wave = tid >> 6, lane = tid & 63;
  const int qcol = lane & 15, quad = lane >> 4;
  const int q_tok = qb * 64 + wave * 16 + qcol;
  const float scale = 0.08838834764831843f;

  __shared__ bf16 KsB[2][64 * 128];   // [key][d]
  __shared__ bf16 VsB[2][128 * 64];   // [d][key]

  const bf16* kbase = Kb + (size_t)g * SEQ * HD;
  const bf16* vbase = Vt + (size_t)g * HD * SEQ;

  // Q B-fragments (held in regs): n = qcol, k = kc*32 + quad*8 + j
  bf16x8 qf[4];
  {
    const bf16* qp = Qb + ((size_t)q_tok * NH + H) * HD + quad * 8;
#pragma unroll
    for (int kc = 0; kc < 4; ++kc) qf[kc] = *(const bf16x8*)(qp + kc * 32);
  }

  float m_i = -1e30f, l_i = 0.f;
  f32x4 o_acc[8] = {};

  const int lr4 = lane >> 4, lc16 = lane & 15;   // K staging lane decomp
  const int lr8 = lane >> 3, lc8 = lane & 7;     // V staging lane decomp

#define STAGE_TILE(buf, key0)                                                  \
  {                                                                            \
    _Pragma("unroll") for (int p2 = 0; p2 < 4; ++p2) {                         \
      int row = p2 * 16 + wave * 4 + lr4;                                      \
      gload_lds16(kbase + (size_t)((key0) + row) * HD + lc16 * 8,              \
                  &KsB[buf][(p2 * 16 + wave * 4) * 128]);                      \
    }                                                                          \
    _Pragma("unroll") for (int p2 = 0; p2 < 4; ++p2) {                         \
      int d = p2 * 32 + wave * 8 + lr8;                                        \
      gload_lds16(vbase + (size_t)d * SEQ + (key0) + lc8 * 8,                  \
                  &VsB[buf][(p2 * 32 + wave * 8) * 64]);                       \
    }                                                                          \
  }

  STAGE_TILE(0, 0)

  for (int kt = 0; kt <= qb; ++kt) {
    __syncthreads();                       // staged buffer ready (vmcnt drain)
    if (kt < qb) STAGE_TILE((kt + 1) & 1, (kt + 1) * 64)
    const bf16* Kt = &KsB[kt & 1][0];
    const bf16* Vtile = &VsB[kt & 1][0];

    // ---- S^T = K · Q^T : A = K rows (m=key), C: col=q(qcol), row=key ----
    f32x4 s[4];
#pragma unroll
    for (int mg = 0; mg < 4; ++mg) {
      f32x4 acc = {0.f, 0.f, 0.f, 0.f};
      const bf16* kr = Kt + (mg * 16 + qcol) * 128 + quad * 8;
#pragma unroll
      for (int kc = 0; kc < 4; ++kc) {
        bf16x8 kf = *(const bf16x8*)(kr + kc * 32);
        acc = __builtin_amdgcn_mfma_f32_16x16x32_bf16(kf, qf[kc], acc, 0, 0, 0);
      }
      s[mg] = acc;
    }

    // ---- V A-frags from LDS (independent of softmax; compiler overlaps) ----
    bf16x8 vf[8][2];
#pragma unroll
    for (int mg2 = 0; mg2 < 8; ++mg2) {
      const bf16* vr = Vtile + (mg2 * 16 + qcol) * 64;
#pragma unroll
      for (int c = 0; c < 2; ++c) {
        bf16x4 v0 = *(const bf16x4*)(vr + c * 32 + quad * 4);
        bf16x4 v1 = *(const bf16x4*)(vr + c * 32 + 16 + quad * 4);
#pragma unroll
        for (int j = 0; j < 4; ++j) { vf[mg2][c][j] = v0[j]; vf[mg2][c][j + 4] = v1[j]; }
      }
    }

    // ---- scale + causal mask + online softmax ----
    float mt = -1e30f;
#pragma unroll
    for (int mg = 0; mg < 4; ++mg)
#pragma unroll
      for (int r = 0; r < 4; ++r) {
        int key = kt * 64 + mg * 16 + quad * 4 + r;
        float v = (key <= q_tok) ? s[mg][r] * scale : -1e30f;
        s[mg][r] = v;
        mt = fmaxf(mt, v);
      }
    mt = fmaxf(mt, __shfl_xor(mt, 16));
    mt = fmaxf(mt, __shfl_xor(mt, 32));
    float mnew = fmaxf(m_i, mt);
    float alpha = __expf(m_i - mnew);
    float ps = 0.f;
#pragma unroll
    for (int mg = 0; mg < 4; ++mg)
#pragma unroll
      for (int r = 0; r < 4; ++r) {
        float pv = __expf(s[mg][r] - mnew);
        s[mg][r] = pv;
        ps += pv;
      }
    ps += __shfl_xor(ps, 16);
    ps += __shfl_xor(ps, 32);
    l_i = l_i * alpha + ps;
    m_i = mnew;
#pragma unroll
    for (int mg2 = 0; mg2 < 8; ++mg2)
#pragma unroll
      for (int r = 0; r < 4; ++r) o_acc[mg2][r] *= alpha;

    // ---- P^T B-frags from own regs (key = mg*16 + quad*4 + r) ----
    bf16x8 pb[2];
#pragma unroll
    for (int c = 0; c < 2; ++c)
#pragma unroll
      for (int j = 0; j < 8; ++j)
        pb[c][j] = (bf16)s[c * 2 + (j >> 2)][j & 3];

    // ---- O^T += V^T · P^T ----
#pragma unroll
    for (int mg2 = 0; mg2 < 8; ++mg2) {
      f32x4 acc = o_acc[mg2];
#pragma unroll
      for (int c = 0; c < 2; ++c)
        acc = __builtin_amdgcn_mfma_f32_16x16x32_bf16(vf[mg2][c], pb[c], acc, 0, 0, 0);
      o_acc[mg2] = acc;
    }
  }

  // ---- normalize + store: O[q_tok][H*128 + d], d = mg2*16 + quad*4 + r ----
  const float inv = 1.f / l_i;
  float* op = O + (size_t)q_tok * DIM + H * HD + quad * 4;
#pragma unroll
  for (int mg2 = 0; mg2 < 8; ++mg2) {
    float4 vv = make_float4(o_acc[mg2][0] * inv, o_acc[mg2][1] * inv,
                            o_acc[mg2][2] * inv, o_acc[mg2][3] * inv);
    *(float4*)(op + mg2 * 16) = vv;
  }
}

// ---------------------------------------------------------------------------
extern "C" void kernel_launch(void* const* d_in, const int* in_sizes, int n_in,
                              void* d_out, int out_size, void* d_ws, size_t ws_size,
                              hipStream_t stream) {
  const float* x      = (const float*)d_in[0];
  const float* w_qkv  = (const float*)d_in[1];
  const float* ws_qkv = (const float*)d_in[2];
  const float* w_o    = (const float*)d_in[3];
  const float* ws_o   = (const float*)d_in[4];
  const float* qnw    = (const float*)d_in[5];
  const float* knw    = (const float*)d_in[6];
  float* out = (float*)d_out;

  char* p = (char*)d_ws;
  bf16*  act1 = (bf16*)p;  p += (size_t)SEQ * DIM * 2;
  float* rs1  = (float*)p; p += 4096;
  bf16*  wqdq = (bf16*)p;  p += (size_t)QKV_OUT * DIM * 2;
  bf16*  wodq = (bf16*)p;  p += (size_t)DIM * DIM * 2;
  float* qkv  = (float*)p; p += (size_t)SEQ * QKV_OUT * 4;
  bf16*  Qb   = (bf16*)p;  p += (size_t)SEQ * NH * HD * 2;
  bf16*  Kb   = (bf16*)p;  p += (size_t)NKV * SEQ * HD * 2;
  bf16*  Vt   = (bf16*)p;  p += (size_t)NKV * HD * SEQ * 2;
  float* attn = (float*)p; p += (size_t)SEQ * DIM * 4;
  bf16*  act2 = (bf16*)p;  p += (size_t)SEQ * DIM * 2;
  float* rs2  = (float*)p; p += 4096;

  quant_kernel<<<SEQ, 256, 0, stream>>>(x, act1, rs1, DIM);
  {
    long t4 = (long)QKV_OUT * DIM / 4;
    dequant_kernel<<<(int)((t4 + 255) / 256), 256, 0, stream>>>(w_qkv, ws_qkv, wqdq, DIM, t4);
  }
  {
    long t4 = (long)DIM * DIM / 4;
    dequant_kernel<<<(int)((t4 + 255) / 256), 256, 0, stream>>>(w_o, ws_o, wodq, DIM, t4);
  }
  gemm_bt<0><<<dim3(QKV_OUT / 128, SEQ / 128), 256, 0, stream>>>(act1, wqdq, rs1, qkv, QKV_OUT, DIM);
  qk_post<<<dim3(SEQ, 25), 64, 0, stream>>>(qkv, qnw, knw, Qb, Kb);
  v_post<<<dim3(SEQ / 64, NKV), 256, 0, stream>>>(qkv, Vt);
  attn_mfma<<<dim3(16, NH), 256, 0, stream>>>(Qb, Kb, Vt, attn);
  quant_kernel<<<SEQ, 256, 0, stream>>>(attn, act2, rs2, DIM);
  gemm_bt<0><<<dim3(DIM / 128, SEQ / 128), 256, 0, stream>>>(act2, wodq, rs2, out, DIM, DIM);
}

// Round 6
// 272.103 us; speedup vs baseline: 1.4651x; 1.4651x over previous
//
#include <hip/hip_runtime.h>
#include <hip/hip_bf16.h>
#include <cstdint>
#include <math.h>

// Problem constants
#define SEQ 1024
#define DIM 2560
#define HD 128
#define NH 20
#define NKV 5
#define QKV_OUT 3840
#define GS 128

typedef __bf16 bf16;
typedef __bf16 bf16x4 __attribute__((ext_vector_type(4)));
typedef __bf16 bf16x8 __attribute__((ext_vector_type(8)));
typedef float f32x4 __attribute__((ext_vector_type(4)));

// ---------------------------------------------------------------------------
// 1) per-token activation quant
// ---------------------------------------------------------------------------
__global__ __launch_bounds__(256) void quant_kernel(
    const float* __restrict__ x, bf16* __restrict__ act,
    float* __restrict__ rs, int cols) {
  const int row = blockIdx.x;
  const int tid = threadIdx.x;
  const float* xr = x + (size_t)row * cols;
  float m = 0.f;
  for (int i = tid; i < cols; i += 256) m = fmaxf(m, fabsf(xr[i]));
  for (int off = 32; off; off >>= 1) m = fmaxf(m, __shfl_xor(m, off));
  __shared__ float red[4];
  __shared__ float s_bc;
  if ((tid & 63) == 0) red[tid >> 6] = m;
  __syncthreads();
  if (tid == 0) {
    float mm = fmaxf(fmaxf(red[0], red[1]), fmaxf(red[2], red[3]));
    mm = fmaxf(mm, 1e-5f);
    s_bc = 127.f / mm;
    rs[row] = mm / 127.f;
  }
  __syncthreads();
  const float s = s_bc;
  bf16* ar = act + (size_t)row * cols;
  for (int i = tid; i < cols; i += 256) {
    float q = rintf(xr[i] * s);
    q = fminf(fmaxf(q, -128.f), 127.f);
    ar[i] = (bf16)q;
  }
}

// ---------------------------------------------------------------------------
// 2) weight dequant: wdq[o,k] = bf16(w[o,k] * ws[o, k/128])
// ---------------------------------------------------------------------------
__global__ __launch_bounds__(256) void dequant_kernel(
    const float* __restrict__ w, const float* __restrict__ ws,
    bf16* __restrict__ wdq, int K, long total4) {
  long i = (long)blockIdx.x * 256 + threadIdx.x;
  if (i >= total4) return;
  long e = i * 4;
  int row = (int)(e / K);
  int k = (int)(e % K);
  float sc = ws[(size_t)row * (K / GS) + (k / GS)];
  float4 wv = *(const float4*)(w + e);
  bf16x4 o;
  o[0] = (bf16)(wv.x * sc);
  o[1] = (bf16)(wv.y * sc);
  o[2] = (bf16)(wv.z * sc);
  o[3] = (bf16)(wv.w * sc);
  *(bf16x4*)(wdq + e) = o;
}

// ---------------------------------------------------------------------------
// 3) bf16 MFMA GEMM, C[m,n] = (sum_k A[m,k]*B[n,k]) * rs[m]
//    Tile 64x128 (M x N) per 256-thr block; more blocks at M=1024.
// ---------------------------------------------------------------------------
__device__ __forceinline__ void gload_lds16(const bf16* g, bf16* l) {
  __builtin_amdgcn_global_load_lds(
      (const __attribute__((address_space(1))) void*)g,
      (__attribute__((address_space(3))) void*)l, 16, 0, 0);
}

template <int OUT_BF16>
__global__ __launch_bounds__(256) void gemm_bt(
    const bf16* __restrict__ A, const bf16* __restrict__ B,
    const float* __restrict__ rs, void* __restrict__ C, int N, int K) {
  __shared__ bf16 As[64 * 64];
  __shared__ bf16 Bs[128 * 64];
  const int tid = threadIdx.x;
  const int w = tid >> 6, l = tid & 63;
  const int row0 = blockIdx.y * 64;
  const int col0 = blockIdx.x * 128;
  const int wm = (w >> 1) * 32, wn = (w & 1) * 64;
  const int lcol = l & 15, quad = l >> 4;
  const int sr = l >> 3;
  const int sk = (l & 7) * 8;
  const bf16* Ag = A + (size_t)row0 * K;
  const bf16* Bg = B + (size_t)col0 * K;

  f32x4 acc[2][4] = {};

  for (int k0 = 0; k0 < K; k0 += 64) {
    __syncthreads();
#pragma unroll
    for (int i = 0; i < 2; ++i) {
      int rb = w * 16 + i * 8;
      gload_lds16(Ag + (size_t)(rb + sr) * K + k0 + sk, As + rb * 64);
    }
#pragma unroll
    for (int i = 0; i < 4; ++i) {
      int rb = w * 32 + i * 8;
      gload_lds16(Bg + (size_t)(rb + sr) * K + k0 + sk, Bs + rb * 64);
    }
    __syncthreads();
#pragma unroll
    for (int ks = 0; ks < 2; ++ks) {
      const int kk = ks * 32 + quad * 8;
      bf16x8 af[2], bff[4];
#pragma unroll
      for (int mi = 0; mi < 2; ++mi)
        af[mi] = *(const bf16x8*)(As + (wm + mi * 16 + lcol) * 64 + kk);
#pragma unroll
      for (int ni = 0; ni < 4; ++ni)
        bff[ni] = *(const bf16x8*)(Bs + (wn + ni * 16 + lcol) * 64 + kk);
#pragma unroll
      for (int mi = 0; mi < 2; ++mi)
#pragma unroll
        for (int ni = 0; ni < 4; ++ni)
          acc[mi][ni] = __builtin_amdgcn_mfma_f32_16x16x32_bf16(
              af[mi], bff[ni], acc[mi][ni], 0, 0, 0);
    }
  }
#pragma unroll
  for (int mi = 0; mi < 2; ++mi) {
#pragma unroll
    for (int ni = 0; ni < 4; ++ni) {
      int col = col0 + wn + ni * 16 + lcol;
#pragma unroll
      for (int r = 0; r < 4; ++r) {
        int row = row0 + wm + mi * 16 + quad * 4 + r;
        float v = acc[mi][ni][r] * rs[row];
        if (OUT_BF16)
          ((bf16*)C)[(size_t)row * N + col] = (bf16)v;
        else
          ((float*)C)[(size_t)row * N + col] = v;
      }
    }
  }
}

// ---------------------------------------------------------------------------
// 4a) q/k postprocess: rmsnorm + rope; bf16. Qo [t][h][d], Ko [g][key][d]
// ---------------------------------------------------------------------------
__global__ void qk_post(const float* __restrict__ qkv,
                        const float* __restrict__ qw, const float* __restrict__ kw,
                        bf16* __restrict__ Qo, bf16* __restrict__ Ko) {
  const int t = blockIdx.x, h = blockIdx.y, i = threadIdx.x;
  const float* src = (h < NH)
      ? qkv + (size_t)t * QKV_OUT + h * HD
      : qkv + (size_t)t * QKV_OUT + 2560 + (h - NH) * HD;
  float x0 = src[2 * i], x1 = src[2 * i + 1];
  float ss = x0 * x0 + x1 * x1;
  for (int off = 1; off < 64; off <<= 1) ss += __shfl_xor(ss, off);
  float r = rsqrtf(ss * (1.f / 128.f) + 1e-5f);
  const float* wv = (h < NH) ? qw : kw;
  float y0 = x0 * r * wv[2 * i];
  float y1 = x1 * r * wv[2 * i + 1];
  float inv_freq = powf(500000.f, -(float)(2 * i) * (1.f / 128.f));
  float ang = (float)t * inv_freq;
  float sn, cs;
  sincosf(ang, &sn, &cs);
  float o0 = y0 * cs - y1 * sn;
  float o1 = y0 * sn + y1 * cs;
  if (h < NH) {
    bf16* dst = Qo + ((size_t)t * NH + h) * HD + 2 * i;
    dst[0] = (bf16)o0; dst[1] = (bf16)o1;
  } else {
    bf16* dst = Ko + ((size_t)(h - NH) * SEQ + t) * HD + 2 * i;
    dst[0] = (bf16)o0; dst[1] = (bf16)o1;
  }
}

// ---------------------------------------------------------------------------
// 4b) V transpose: qkv fp32 [t][3200+g*128+d] -> Vt bf16 [g][d][t]
// ---------------------------------------------------------------------------
__global__ __launch_bounds__(256) void v_post(const float* __restrict__ qkv,
                                              bf16* __restrict__ Vt) {
  const int t0 = blockIdx.x * 64, g = blockIdx.y;
  const int tid = threadIdx.x;
  __shared__ bf16 Ls[64 * 137];
  {
    const int tl = tid >> 4;
    const int d0 = (tid & 15) * 8;
#pragma unroll
    for (int pass = 0; pass < 4; ++pass) {
      int t = pass * 16 + tl;
      const float* src = qkv + (size_t)(t0 + t) * QKV_OUT + 3200 + g * HD + d0;
      float4 a = *(const float4*)src;
      float4 b = *(const float4*)(src + 4);
      bf16* dst = Ls + t * 137 + d0;
      dst[0] = (bf16)a.x; dst[1] = (bf16)a.y; dst[2] = (bf16)a.z; dst[3] = (bf16)a.w;
      dst[4] = (bf16)b.x; dst[5] = (bf16)b.y; dst[6] = (bf16)b.z; dst[7] = (bf16)b.w;
    }
  }
  __syncthreads();
  {
    const int dl = tid >> 3;
    const int tl0 = (tid & 7) * 8;
#pragma unroll
    for (int pass = 0; pass < 4; ++pass) {
      int d = pass * 32 + dl;
      bf16x8 v;
#pragma unroll
      for (int j = 0; j < 8; ++j) v[j] = Ls[(tl0 + j) * 137 + d];
      *(bf16x8*)(Vt + ((size_t)g * HD + d) * SEQ + t0 + tl0) = v;
    }
  }
}

// ---------------------------------------------------------------------------
// 5) MFMA GQA causal flash attention, LDS-staged with XOR swizzle.
//    Block = 128 thr (2 waves) per (32-q band, head); wave w owns q-rows
//    [qb*32+w*16, +16). K (64x128) and V^T (128x64) staged via
//    global_load_lds w16 with the inverse swizzle applied on the GLOBAL
//    address side; LDS slot s of row r holds 16B-group s^(r&mask).
//    K reads -> 2-way (free); V reads -> conflict-free.
// ---------------------------------------------------------------------------
__global__ __launch_bounds__(128) void attn_mfma(
    const bf16* __restrict__ Qb, const bf16* __restrict__ Kb,
    const bf16* __restrict__ Vt, float* __restrict__ O) {
  const int qb = 31 - (int)blockIdx.x;     // long blocks first
  const int H = blockIdx.y, g = H >> 2;
  const int tid = threadIdx.x;
  const int wave = tid >> 6, lane = tid & 63;
  const int qcol = lane & 15, quad = lane >> 4;
  const int q_tok = qb * 32 + wave * 16 + qcol;
  const float scale = 0.08838834764831843f;

  __shared__ bf16 Ks[64 * 128];   // [key][d], d 16B-groups swizzled by key&15
  __shared__ bf16 Vs[128 * 64];   // [d][key], key 16B-groups swizzled by d&7

  const bf16* kbase = Kb + (size_t)g * SEQ * HD;
  const bf16* vbase = Vt + (size_t)g * HD * SEQ;

  bf16x8 qf[4];
  {
    const bf16* qp = Qb + ((size_t)q_tok * NH + H) * HD + quad * 8;
#pragma unroll
    for (int kc = 0; kc < 4; ++kc) qf[kc] = *(const bf16x8*)(qp + kc * 32);
  }

  float m_i = -1e30f, l_i = 0.f;
  f32x4 o_acc[8] = {};
  const int kt_max = (qb * 32 + 31) >> 6;

  const int k_r = lane >> 4, k_g = lane & 15;  // K staging: 4 rows/instr
  const int v_r = lane >> 3, v_g = lane & 7;   // V staging: 8 rows/instr

  for (int kt = 0; kt <= kt_max; ++kt) {
    const int key0 = kt * 64;
    __syncthreads();                 // prior compute done before overwrite
    // stage K: 8 instrs/wave, 4 rows each; fetch swizzled group
#pragma unroll
    for (int p = 0; p < 8; ++p) {
      int r0 = (wave * 8 + p) * 4;
      int r = r0 + k_r;
      gload_lds16(kbase + (size_t)(key0 + r) * HD + ((k_g ^ (r & 15)) * 8),
                  Ks + r0 * 128);
    }
    // stage V: 8 instrs/wave, 8 rows each
#pragma unroll
    for (int p = 0; p < 8; ++p) {
      int r0 = (wave * 8 + p) * 8;
      int r = r0 + v_r;
      gload_lds16(vbase + (size_t)r * SEQ + key0 + ((v_g ^ (r & 7)) * 8),
                  Vs + r0 * 64);
    }
    __syncthreads();                 // staged data visible (vmcnt drained)

    // ---- S^T = K · Q^T : A-frag row R=key, k-group j = kc*4+quad ----
    f32x4 s[4];
#pragma unroll
    for (int mg = 0; mg < 4; ++mg) {
      const int R = mg * 16 + qcol;
      const bf16* krow = Ks + R * 128;
      f32x4 acc = {0.f, 0.f, 0.f, 0.f};
#pragma unroll
      for (int kc = 0; kc < 4; ++kc) {
        int j = kc * 4 + quad;
        bf16x8 kf = *(const bf16x8*)(krow + ((j ^ (R & 15)) * 8));
        acc = __builtin_amdgcn_mfma_f32_16x16x32_bf16(kf, qf[kc], acc, 0, 0, 0);
      }
      s[mg] = acc;
    }

    // ---- scale + causal mask + online softmax ----
    float mt = -1e30f;
#pragma unroll
    for (int mg = 0; mg < 4; ++mg)
#pragma unroll
      for (int r = 0; r < 4; ++r) {
        int key = key0 + mg * 16 + quad * 4 + r;
        float v = (key <= q_tok) ? s[mg][r] * scale : -1e30f;
        s[mg][r] = v;
        mt = fmaxf(mt, v);
      }
    mt = fmaxf(mt, __shfl_xor(mt, 16));
    mt = fmaxf(mt, __shfl_xor(mt, 32));
    float mnew = fmaxf(m_i, mt);
    float alpha = __expf(m_i - mnew);
    float ps = 0.f;
#pragma unroll
    for (int mg = 0; mg < 4; ++mg)
#pragma unroll
      for (int r = 0; r < 4; ++r) {
        float pv = __expf(s[mg][r] - mnew);
        s[mg][r] = pv;
        ps += pv;
      }
    ps += __shfl_xor(ps, 16);
    ps += __shfl_xor(ps, 32);
    l_i = l_i * alpha + ps;
    m_i = mnew;
#pragma unroll
    for (int mg2 = 0; mg2 < 8; ++mg2)
#pragma unroll
      for (int r = 0; r < 4; ++r) o_acc[mg2][r] *= alpha;

    // ---- P^T B-frags from own regs (key = mg*16 + quad*4 + r) ----
    bf16x8 pb[2];
#pragma unroll
    for (int c = 0; c < 2; ++c)
#pragma unroll
      for (int j = 0; j < 8; ++j)
        pb[c][j] = (bf16)s[c * 2 + (j >> 2)][j & 3];

    // ---- O^T += V^T · P^T (V A-frags from swizzled LDS, 8B granules) ----
#pragma unroll
    for (int mg2 = 0; mg2 < 8; ++mg2) {
      const int R = mg2 * 16 + qcol;
      const bf16* vrow = Vs + R * 64;
      f32x4 acc = o_acc[mg2];
#pragma unroll
      for (int c = 0; c < 2; ++c) {
        int g8a = c * 8 + quad;
        int g8b = c * 8 + 4 + quad;
        bf16x4 v0 = *(const bf16x4*)(vrow + ((g8a >> 1) ^ (R & 7)) * 8 + (g8a & 1) * 4);
        bf16x4 v1 = *(const bf16x4*)(vrow + ((g8b >> 1) ^ (R & 7)) * 8 + (g8b & 1) * 4);
        bf16x8 vfr;
#pragma unroll
        for (int j = 0; j < 4; ++j) { vfr[j] = v0[j]; vfr[j + 4] = v1[j]; }
        acc = __builtin_amdgcn_mfma_f32_16x16x32_bf16(vfr, pb[c], acc, 0, 0, 0);
      }
      o_acc[mg2] = acc;
    }
  }

  // ---- normalize + store ----
  const float inv = 1.f / l_i;
  float* op = O + (size_t)q_tok * DIM + H * HD + quad * 4;
#pragma unroll
  for (int mg2 = 0; mg2 < 8; ++mg2) {
    float4 vv = make_float4(o_acc[mg2][0] * inv, o_acc[mg2][1] * inv,
                            o_acc[mg2][2] * inv, o_acc[mg2][3] * inv);
    *(float4*)(op + mg2 * 16) = vv;
  }
}

// ---------------------------------------------------------------------------
extern "C" void kernel_launch(void* const* d_in, const int* in_sizes, int n_in,
                              void* d_out, int out_size, void* d_ws, size_t ws_size,
                              hipStream_t stream) {
  const float* x      = (const float*)d_in[0];
  const float* w_qkv  = (const float*)d_in[1];
  const float* ws_qkv = (const float*)d_in[2];
  const float* w_o    = (const float*)d_in[3];
  const float* ws_o   = (const float*)d_in[4];
  const float* qnw    = (const float*)d_in[5];
  const float* knw    = (const float*)d_in[6];
  float* out = (float*)d_out;

  char* p = (char*)d_ws;
  bf16*  act1 = (bf16*)p;  p += (size_t)SEQ * DIM * 2;
  float* rs1  = (float*)p; p += 4096;
  bf16*  wqdq = (bf16*)p;  p += (size_t)QKV_OUT * DIM * 2;
  bf16*  wodq = (bf16*)p;  p += (size_t)DIM * DIM * 2;
  float* qkv  = (float*)p; p += (size_t)SEQ * QKV_OUT * 4;
  bf16*  Qb   = (bf16*)p;  p += (size_t)SEQ * NH * HD * 2;
  bf16*  Kb   = (bf16*)p;  p += (size_t)NKV * SEQ * HD * 2;
  bf16*  Vt   = (bf16*)p;  p += (size_t)NKV * HD * SEQ * 2;
  float* attn = (float*)p; p += (size_t)SEQ * DIM * 4;
  bf16*  act2 = (bf16*)p;  p += (size_t)SEQ * DIM * 2;
  float* rs2  = (float*)p; p += 4096;

  quant_kernel<<<SEQ, 256, 0, stream>>>(x, act1, rs1, DIM);
  {
    long t4 = (long)QKV_OUT * DIM / 4;
    dequant_kernel<<<(int)((t4 + 255) / 256), 256, 0, stream>>>(w_qkv, ws_qkv, wqdq, DIM, t4);
  }
  {
    long t4 = (long)DIM * DIM / 4;
    dequant_kernel<<<(int)((t4 + 255) / 256), 256, 0, stream>>>(w_o, ws_o, wodq, DIM, t4);
  }
  gemm_bt<0><<<dim3(QKV_OUT / 128, SEQ / 64), 256, 0, stream>>>(act1, wqdq, rs1, qkv, QKV_OUT, DIM);
  qk_post<<<dim3(SEQ, 25), 64, 0, stream>>>(qkv, qnw, knw, Qb, Kb);
  v_post<<<dim3(SEQ / 64, NKV), 256, 0, stream>>>(qkv, Vt);
  attn_mfma<<<dim3(32, NH), 128, 0, stream>>>(Qb, Kb, Vt, attn);
  quant_kernel<<<SEQ, 256, 0, stream>>>(attn, act2, rs2, DIM);
  gemm_bt<0><<<dim3(DIM / 128, SEQ / 64), 256, 0, stream>>>(act2, wodq, rs2, out, DIM, DIM);
}

// Round 8
// 246.612 us; speedup vs baseline: 1.6165x; 1.1034x over previous
//
#include <hip/hip_runtime.h>
#include <hip/hip_bf16.h>
#include <cstdint>
#include <math.h>

// Problem constants
#define SEQ 1024
#define DIM 2560
#define HD 128
#define NH 20
#define NKV 5
#define QKV_OUT 3840
#define GS 128

typedef __bf16 bf16;
typedef __bf16 bf16x4 __attribute__((ext_vector_type(4)));
typedef __bf16 bf16x8 __attribute__((ext_vector_type(8)));
typedef float f32x4 __attribute__((ext_vector_type(4)));

// ---------------------------------------------------------------------------
// 1) per-token activation quant
// ---------------------------------------------------------------------------
__global__ __launch_bounds__(256) void quant_kernel(
    const float* __restrict__ x, bf16* __restrict__ act,
    float* __restrict__ rs, int cols) {
  const int row = blockIdx.x;
  const int tid = threadIdx.x;
  const float* xr = x + (size_t)row * cols;
  float m = 0.f;
  for (int i = tid; i < cols; i += 256) m = fmaxf(m, fabsf(xr[i]));
  for (int off = 32; off; off >>= 1) m = fmaxf(m, __shfl_xor(m, off));
  __shared__ float red[4];
  __shared__ float s_bc;
  if ((tid & 63) == 0) red[tid >> 6] = m;
  __syncthreads();
  if (tid == 0) {
    float mm = fmaxf(fmaxf(red[0], red[1]), fmaxf(red[2], red[3]));
    mm = fmaxf(mm, 1e-5f);
    s_bc = 127.f / mm;
    rs[row] = mm / 127.f;
  }
  __syncthreads();
  const float s = s_bc;
  bf16* ar = act + (size_t)row * cols;
  for (int i = tid; i < cols; i += 256) {
    float q = rintf(xr[i] * s);
    q = fminf(fmaxf(q, -128.f), 127.f);
    ar[i] = (bf16)q;
  }
}

// ---------------------------------------------------------------------------
// 2) weight dequant: wdq[o,k] = bf16(w[o,k] * ws[o, k/128])
// ---------------------------------------------------------------------------
__global__ __launch_bounds__(256) void dequant_kernel(
    const float* __restrict__ w, const float* __restrict__ ws,
    bf16* __restrict__ wdq, int K, long total4) {
  long i = (long)blockIdx.x * 256 + threadIdx.x;
  if (i >= total4) return;
  long e = i * 4;
  int row = (int)(e / K);
  int k = (int)(e % K);
  float sc = ws[(size_t)row * (K / GS) + (k / GS)];
  float4 wv = *(const float4*)(w + e);
  bf16x4 o;
  o[0] = (bf16)(wv.x * sc);
  o[1] = (bf16)(wv.y * sc);
  o[2] = (bf16)(wv.z * sc);
  o[3] = (bf16)(wv.w * sc);
  *(bf16x4*)(wdq + e) = o;
}

// ---------------------------------------------------------------------------
// 3) bf16 MFMA GEMM, split-K x2, XOR-swizzled LDS.
//    C_partial[z][m,n] = (sum_{k in half z} A[m,k]*B[n,k]) * rs[m]
// ---------------------------------------------------------------------------
__device__ __forceinline__ void gload_lds16(const bf16* g, bf16* l) {
  __builtin_amdgcn_global_load_lds(
      (const __attribute__((address_space(1))) void*)g,
      (__attribute__((address_space(3))) void*)l, 16, 0, 0);
}

__global__ __launch_bounds__(256) void gemm_bt(
    const bf16* __restrict__ A, const bf16* __restrict__ B,
    const float* __restrict__ rs, float* __restrict__ C,
    int N, int K, int Kh, size_t part_stride) {
  __shared__ bf16 As[64 * 64];
  __shared__ bf16 Bs[128 * 64];
  const int tid = threadIdx.x;
  const int w = tid >> 6, l = tid & 63;
  const int row0 = blockIdx.y * 64;
  const int col0 = blockIdx.x * 128;
  const int z = blockIdx.z;
  const int wm = (w >> 1) * 32, wn = (w & 1) * 64;
  const int lcol = l & 15, quad = l >> 4;
  const int sr = l >> 3;          // staging row within 8-row slab
  const int sg = l & 7;           // staging 16B-group
  const bf16* Ag = A + (size_t)row0 * K + (size_t)z * Kh;
  const bf16* Bg = B + (size_t)col0 * K + (size_t)z * Kh;

  f32x4 acc[2][4] = {};

  for (int k0 = 0; k0 < Kh; k0 += 64) {
    __syncthreads();
#pragma unroll
    for (int i = 0; i < 2; ++i) {
      int rb = w * 16 + i * 8;
      int r = rb + sr;
      gload_lds16(Ag + (size_t)r * K + k0 + ((sg ^ (r & 7)) * 8), As + rb * 64);
    }
#pragma unroll
    for (int i = 0; i < 4; ++i) {
      int rb = w * 32 + i * 8;
      int r = rb + sr;
      gload_lds16(Bg + (size_t)r * K + k0 + ((sg ^ (r & 7)) * 8), Bs + rb * 64);
    }
    __syncthreads();
#pragma unroll
    for (int ks = 0; ks < 2; ++ks) {
      bf16x8 af[2], bff[4];
#pragma unroll
      for (int mi = 0; mi < 2; ++mi) {
        int R = wm + mi * 16 + lcol;
        af[mi] = *(const bf16x8*)(As + R * 64 + (((ks * 4 + quad) ^ (R & 7)) * 8));
      }
#pragma unroll
      for (int ni = 0; ni < 4; ++ni) {
        int R = wn + ni * 16 + lcol;
        bff[ni] = *(const bf16x8*)(Bs + R * 64 + (((ks * 4 + quad) ^ (R & 7)) * 8));
      }
#pragma unroll
      for (int mi = 0; mi < 2; ++mi)
#pragma unroll
        for (int ni = 0; ni < 4; ++ni)
          acc[mi][ni] = __builtin_amdgcn_mfma_f32_16x16x32_bf16(
              af[mi], bff[ni], acc[mi][ni], 0, 0, 0);
    }
  }
  float* Cp = C + (size_t)z * part_stride;
#pragma unroll
  for (int mi = 0; mi < 2; ++mi) {
#pragma unroll
    for (int ni = 0; ni < 4; ++ni) {
      int col = col0 + wn + ni * 16 + lcol;
#pragma unroll
      for (int r = 0; r < 4; ++r) {
        int row = row0 + wm + mi * 16 + quad * 4 + r;
        Cp[(size_t)row * N + col] = acc[mi][ni][r] * rs[row];
      }
    }
  }
}

// ---------------------------------------------------------------------------
// 3b) elementwise add of two split-K partials
// ---------------------------------------------------------------------------
__global__ __launch_bounds__(256) void add2_kernel(
    const float* __restrict__ a, const float* __restrict__ b,
    float* __restrict__ o, int n4) {
  int i = blockIdx.x * 256 + threadIdx.x;
  if (i >= n4) return;
  float4 x = ((const float4*)a)[i];
  float4 y = ((const float4*)b)[i];
  ((float4*)o)[i] = make_float4(x.x + y.x, x.y + y.y, x.z + y.z, x.w + y.w);
}

// ---------------------------------------------------------------------------
// 4a) q/k postprocess: sum split-K partials + rmsnorm + rope; bf16 out.
// ---------------------------------------------------------------------------
__global__ void qk_post(const float* __restrict__ qkvA, const float* __restrict__ qkvB,
                        const float* __restrict__ qw, const float* __restrict__ kw,
                        bf16* __restrict__ Qo, bf16* __restrict__ Ko) {
  const int t = blockIdx.x, h = blockIdx.y, i = threadIdx.x;
  const size_t off = (h < NH)
      ? (size_t)t * QKV_OUT + h * HD
      : (size_t)t * QKV_OUT + 2560 + (h - NH) * HD;
  const float* s1 = qkvA + off;
  const float* s2 = qkvB + off;
  float x0 = s1[2 * i] + s2[2 * i];
  float x1 = s1[2 * i + 1] + s2[2 * i + 1];
  float ss = x0 * x0 + x1 * x1;
  for (int off2 = 1; off2 < 64; off2 <<= 1) ss += __shfl_xor(ss, off2);
  float r = rsqrtf(ss * (1.f / 128.f) + 1e-5f);
  const float* wv = (h < NH) ? qw : kw;
  float y0 = x0 * r * wv[2 * i];
  float y1 = x1 * r * wv[2 * i + 1];
  float inv_freq = powf(500000.f, -(float)(2 * i) * (1.f / 128.f));
  float ang = (float)t * inv_freq;
  float sn, cs;
  sincosf(ang, &sn, &cs);
  float o0 = y0 * cs - y1 * sn;
  float o1 = y0 * sn + y1 * cs;
  if (h < NH) {
    bf16* dst = Qo + ((size_t)t * NH + h) * HD + 2 * i;
    dst[0] = (bf16)o0; dst[1] = (bf16)o1;
  } else {
    bf16* dst = Ko + ((size_t)(h - NH) * SEQ + t) * HD + 2 * i;
    dst[0] = (bf16)o0; dst[1] = (bf16)o1;
  }
}

// ---------------------------------------------------------------------------
// 4b) V transpose: sum partials, fp32 [t][3200+g*128+d] -> Vt bf16 [g][d][t]
// ---------------------------------------------------------------------------
__global__ __launch_bounds__(256) void v_post(const float* __restrict__ qkvA,
                                              const float* __restrict__ qkvB,
                                              bf16* __restrict__ Vt) {
  const int t0 = blockIdx.x * 64, g = blockIdx.y;
  const int tid = threadIdx.x;
  __shared__ bf16 Ls[64 * 137];
  {
    const int tl = tid >> 4;
    const int d0 = (tid & 15) * 8;
#pragma unroll
    for (int pass = 0; pass < 4; ++pass) {
      int t = pass * 16 + tl;
      size_t off = (size_t)(t0 + t) * QKV_OUT + 3200 + g * HD + d0;
      float4 a = *(const float4*)(qkvA + off);
      float4 b = *(const float4*)(qkvA + off + 4);
      float4 a2 = *(const float4*)(qkvB + off);
      float4 b2 = *(const float4*)(qkvB + off + 4);
      bf16* dst = Ls + t * 137 + d0;
      dst[0] = (bf16)(a.x + a2.x); dst[1] = (bf16)(a.y + a2.y);
      dst[2] = (bf16)(a.z + a2.z); dst[3] = (bf16)(a.w + a2.w);
      dst[4] = (bf16)(b.x + b2.x); dst[5] = (bf16)(b.y + b2.y);
      dst[6] = (bf16)(b.z + b2.z); dst[7] = (bf16)(b.w + b2.w);
    }
  }
  __syncthreads();
  {
    const int dl = tid >> 3;
    const int tl0 = (tid & 7) * 8;
#pragma unroll
    for (int pass = 0; pass < 4; ++pass) {
      int d = pass * 32 + dl;
      bf16x8 v;
#pragma unroll
      for (int j = 0; j < 8; ++j) v[j] = Ls[(tl0 + j) * 137 + d];
      *(bf16x8*)(Vt + ((size_t)g * HD + d) * SEQ + t0 + tl0) = v;
    }
  }
}

// ---------------------------------------------------------------------------
// 5) MFMA GQA causal flash attention, LDS-staged with XOR swizzle.
// ---------------------------------------------------------------------------
__global__ __launch_bounds__(128) void attn_mfma(
    const bf16* __restrict__ Qb, const bf16* __restrict__ Kb,
    const bf16* __restrict__ Vt, float* __restrict__ O) {
  const int qb = 31 - (int)blockIdx.x;     // long blocks first
  const int H = blockIdx.y, g = H >> 2;
  const int tid = threadIdx.x;
  const int wave = tid >> 6, lane = tid & 63;
  const int qcol = lane & 15, quad = lane >> 4;
  const int q_tok = qb * 32 + wave * 16 + qcol;
  const float scale = 0.08838834764831843f;

  __shared__ bf16 Ks[64 * 128];   // [key][d], d 16B-groups swizzled by key&15
  __shared__ bf16 Vs[128 * 64];   // [d][key], key 16B-groups swizzled by d&7

  const bf16* kbase = Kb + (size_t)g * SEQ * HD;
  const bf16* vbase = Vt + (size_t)g * HD * SEQ;

  bf16x8 qf[4];
  {
    const bf16* qp = Qb + ((size_t)q_tok * NH + H) * HD + quad * 8;
#pragma unroll
    for (int kc = 0; kc < 4; ++kc) qf[kc] = *(const bf16x8*)(qp + kc * 32);
  }

  float m_i = -1e30f, l_i = 0.f;
  f32x4 o_acc[8] = {};
  const int kt_max = (qb * 32 + 31) >> 6;

  const int k_r = lane >> 4, k_g = lane & 15;
  const int v_r = lane >> 3, v_g = lane & 7;

  for (int kt = 0; kt <= kt_max; ++kt) {
    const int key0 = kt * 64;
    __syncthreads();
#pragma unroll
    for (int p = 0; p < 8; ++p) {
      int r0 = (wave * 8 + p) * 4;
      int r = r0 + k_r;
      gload_lds16(kbase + (size_t)(key0 + r) * HD + ((k_g ^ (r & 15)) * 8),
                  Ks + r0 * 128);
    }
#pragma unroll
    for (int p = 0; p < 8; ++p) {
      int r0 = (wave * 8 + p) * 8;
      int r = r0 + v_r;
      gload_lds16(vbase + (size_t)r * SEQ + key0 + ((v_g ^ (r & 7)) * 8),
                  Vs + r0 * 64);
    }
    __syncthreads();

    f32x4 s[4];
#pragma unroll
    for (int mg = 0; mg < 4; ++mg) {
      const int R = mg * 16 + qcol;
      const bf16* krow = Ks + R * 128;
      f32x4 acc = {0.f, 0.f, 0.f, 0.f};
#pragma unroll
      for (int kc = 0; kc < 4; ++kc) {
        int j = kc * 4 + quad;
        bf16x8 kf = *(const bf16x8*)(krow + ((j ^ (R & 15)) * 8));
        acc = __builtin_amdgcn_mfma_f32_16x16x32_bf16(kf, qf[kc], acc, 0, 0, 0);
      }
      s[mg] = acc;
    }

    float mt = -1e30f;
#pragma unroll
    for (int mg = 0; mg < 4; ++mg)
#pragma unroll
      for (int r = 0; r < 4; ++r) {
        int key = key0 + mg * 16 + quad * 4 + r;
        float v = (key <= q_tok) ? s[mg][r] * scale : -1e30f;
        s[mg][r] = v;
        mt = fmaxf(mt, v);
      }
    mt = fmaxf(mt, __shfl_xor(mt, 16));
    mt = fmaxf(mt, __shfl_xor(mt, 32));
    float mnew = fmaxf(m_i, mt);
    float alpha = __expf(m_i - mnew);
    float ps = 0.f;
#pragma unroll
    for (int mg = 0; mg < 4; ++mg)
#pragma unroll
      for (int r = 0; r < 4; ++r) {
        float pv = __expf(s[mg][r] - mnew);
        s[mg][r] = pv;
        ps += pv;
      }
    ps += __shfl_xor(ps, 16);
    ps += __shfl_xor(ps, 32);
    l_i = l_i * alpha + ps;
    m_i = mnew;
#pragma unroll
    for (int mg2 = 0; mg2 < 8; ++mg2)
#pragma unroll
      for (int r = 0; r < 4; ++r) o_acc[mg2][r] *= alpha;

    bf16x8 pb[2];
#pragma unroll
    for (int c = 0; c < 2; ++c)
#pragma unroll
      for (int j = 0; j < 8; ++j)
        pb[c][j] = (bf16)s[c * 2 + (j >> 2)][j & 3];

#pragma unroll
    for (int mg2 = 0; mg2 < 8; ++mg2) {
      const int R = mg2 * 16 + qcol;
      const bf16* vrow = Vs + R * 64;
      f32x4 acc = o_acc[mg2];
#pragma unroll
      for (int c = 0; c < 2; ++c) {
        int g8a = c * 8 + quad;
        int g8b = c * 8 + 4 + quad;
        bf16x4 v0 = *(const bf16x4*)(vrow + ((g8a >> 1) ^ (R & 7)) * 8 + (g8a & 1) * 4);
        bf16x4 v1 = *(const bf16x4*)(vrow + ((g8b >> 1) ^ (R & 7)) * 8 + (g8b & 1) * 4);
        bf16x8 vfr;
#pragma unroll
        for (int j = 0; j < 4; ++j) { vfr[j] = v0[j]; vfr[j + 4] = v1[j]; }
        acc = __builtin_amdgcn_mfma_f32_16x16x32_bf16(vfr, pb[c], acc, 0, 0, 0);
      }
      o_acc[mg2] = acc;
    }
  }

  const float inv = 1.f / l_i;
  float* op = O + (size_t)q_tok * DIM + H * HD + quad * 4;
#pragma unroll
  for (int mg2 = 0; mg2 < 8; ++mg2) {
    float4 vv = make_float4(o_acc[mg2][0] * inv, o_acc[mg2][1] * inv,
                            o_acc[mg2][2] * inv, o_acc[mg2][3] * inv);
    *(float4*)(op + mg2 * 16) = vv;
  }
}

// ---------------------------------------------------------------------------
extern "C" void kernel_launch(void* const* d_in, const int* in_sizes, int n_in,
                              void* d_out, int out_size, void* d_ws, size_t ws_size,
                              hipStream_t stream) {
  const float* x      = (const float*)d_in[0];
  const float* w_qkv  = (const float*)d_in[1];
  const float* ws_qkv = (const float*)d_in[2];
  const float* w_o    = (const float*)d_in[3];
  const float* ws_o   = (const float*)d_in[4];
  const float* qnw    = (const float*)d_in[5];
  const float* knw    = (const float*)d_in[6];
  float* out = (float*)d_out;

  char* p = (char*)d_ws;
  bf16*  act1 = (bf16*)p;  p += (size_t)SEQ * DIM * 2;
  float* rs1  = (float*)p; p += 4096;
  bf16*  wqdq = (bf16*)p;  p += (size_t)QKV_OUT * DIM * 2;
  bf16*  wodq = (bf16*)p;  p += (size_t)DIM * DIM * 2;
  float* qkvA = (float*)p; p += (size_t)SEQ * QKV_OUT * 4;
  float* qkvB = (float*)p; p += (size_t)SEQ * QKV_OUT * 4;
  bf16*  Qb   = (bf16*)p;  p += (size_t)SEQ * NH * HD * 2;
  bf16*  Kb   = (bf16*)p;  p += (size_t)NKV * SEQ * HD * 2;
  bf16*  Vt   = (bf16*)p;  p += (size_t)NKV * HD * SEQ * 2;
  float* attn = (float*)p; p += (size_t)SEQ * DIM * 4;
  bf16*  act2 = (bf16*)p;  p += (size_t)SEQ * DIM * 2;
  float* rs2  = (float*)p; p += 4096;

  // O-projection partials: z=0 at outA, z=1 at outA + SEQ*DIM (matches
  // part_stride!). qkvA/qkvB region is SEQ*7680 floats >= SEQ*5120 needed.
  float* outA = qkvA;
  float* outB = qkvA + (size_t)SEQ * DIM;

  quant_kernel<<<SEQ, 256, 0, stream>>>(x, act1, rs1, DIM);
  {
    long t4 = (long)QKV_OUT * DIM / 4;
    dequant_kernel<<<(int)((t4 + 255) / 256), 256, 0, stream>>>(w_qkv, ws_qkv, wqdq, DIM, t4);
  }
  {
    long t4 = (long)DIM * DIM / 4;
    dequant_kernel<<<(int)((t4 + 255) / 256), 256, 0, stream>>>(w_o, ws_o, wodq, DIM, t4);
  }
  gemm_bt<<<dim3(QKV_OUT / 128, SEQ / 64, 2), 256, 0, stream>>>(
      act1, wqdq, rs1, qkvA, QKV_OUT, DIM, DIM / 2, (size_t)SEQ * QKV_OUT);
  qk_post<<<dim3(SEQ, 25), 64, 0, stream>>>(qkvA, qkvB, qnw, knw, Qb, Kb);
  v_post<<<dim3(SEQ / 64, NKV), 256, 0, stream>>>(qkvA, qkvB, Vt);
  attn_mfma<<<dim3(32, NH), 128, 0, stream>>>(Qb, Kb, Vt, attn);
  quant_kernel<<<SEQ, 256, 0, stream>>>(attn, act2, rs2, DIM);
  gemm_bt<<<dim3(DIM / 128, SEQ / 64, 2), 256, 0, stream>>>(
      act2, wodq, rs2, outA, DIM, DIM, DIM / 2, (size_t)SEQ * DIM);
  {
    int n4 = SEQ * DIM / 4;
    add2_kernel<<<(n4 + 255) / 256, 256, 0, stream>>>(outA, outB, out, n4);
  }
}

// Round 9
// 242.906 us; speedup vs baseline: 1.6412x; 1.0153x over previous
//
#include <hip/hip_runtime.h>
#include <hip/hip_bf16.h>
#include <cstdint>
#include <math.h>

// Problem constants
#define SEQ 1024
#define DIM 2560
#define HD 128
#define NH 20
#define NKV 5
#define QKV_OUT 3840
#define GS 128

typedef __bf16 bf16;
typedef __bf16 bf16x4 __attribute__((ext_vector_type(4)));
typedef __bf16 bf16x8 __attribute__((ext_vector_type(8)));
typedef float f32x4 __attribute__((ext_vector_type(4)));

// ---------------------------------------------------------------------------
// 1) per-token activation quant (templated input dtype)
// ---------------------------------------------------------------------------
template <typename T>
__global__ __launch_bounds__(256) void quant_kernel(
    const T* __restrict__ x, bf16* __restrict__ act,
    float* __restrict__ rs, int cols) {
  const int row = blockIdx.x;
  const int tid = threadIdx.x;
  const T* xr = x + (size_t)row * cols;
  float m = 0.f;
  for (int i = tid; i < cols; i += 256) m = fmaxf(m, fabsf((float)xr[i]));
  for (int off = 32; off; off >>= 1) m = fmaxf(m, __shfl_xor(m, off));
  __shared__ float red[4];
  __shared__ float s_bc;
  if ((tid & 63) == 0) red[tid >> 6] = m;
  __syncthreads();
  if (tid == 0) {
    float mm = fmaxf(fmaxf(red[0], red[1]), fmaxf(red[2], red[3]));
    mm = fmaxf(mm, 1e-5f);
    s_bc = 127.f / mm;
    rs[row] = mm / 127.f;
  }
  __syncthreads();
  const float s = s_bc;
  bf16* ar = act + (size_t)row * cols;
  for (int i = tid; i < cols; i += 256) {
    float q = rintf((float)xr[i] * s);
    q = fminf(fmaxf(q, -128.f), 127.f);
    ar[i] = (bf16)q;
  }
}

// ---------------------------------------------------------------------------
// 2) merged weight dequant for both weight matrices (K = DIM for both)
// ---------------------------------------------------------------------------
__global__ __launch_bounds__(256) void dequant2_kernel(
    const float* __restrict__ w1, const float* __restrict__ ws1, bf16* __restrict__ o1,
    const float* __restrict__ w2, const float* __restrict__ ws2, bf16* __restrict__ o2,
    long n1_4, long total4) {
  long i = (long)blockIdx.x * 256 + threadIdx.x;
  if (i >= total4) return;
  const float* w; const float* ws; bf16* o; long e;
  if (i < n1_4) { w = w1; ws = ws1; o = o1; e = i * 4; }
  else          { w = w2; ws = ws2; o = o2; e = (i - n1_4) * 4; }
  int row = (int)(e / DIM);
  int k = (int)(e % DIM);
  float sc = ws[(size_t)row * (DIM / GS) + (k / GS)];
  float4 wv = *(const float4*)(w + e);
  bf16x4 ov;
  ov[0] = (bf16)(wv.x * sc);
  ov[1] = (bf16)(wv.y * sc);
  ov[2] = (bf16)(wv.z * sc);
  ov[3] = (bf16)(wv.w * sc);
  *(bf16x4*)(o + e) = ov;
}

// ---------------------------------------------------------------------------
// 3a) bf16 MFMA GEMM, split-K x2, XOR-swizzled LDS (64x128 tile) -> partials
// ---------------------------------------------------------------------------
__device__ __forceinline__ void gload_lds16(const bf16* g, bf16* l) {
  __builtin_amdgcn_global_load_lds(
      (const __attribute__((address_space(1))) void*)g,
      (__attribute__((address_space(3))) void*)l, 16, 0, 0);
}

__global__ __launch_bounds__(256) void gemm_bt(
    const bf16* __restrict__ A, const bf16* __restrict__ B,
    const float* __restrict__ rs, float* __restrict__ C,
    int N, int K, int Kh, size_t part_stride) {
  __shared__ bf16 As[64 * 64];
  __shared__ bf16 Bs[128 * 64];
  const int tid = threadIdx.x;
  const int w = tid >> 6, l = tid & 63;
  const int row0 = blockIdx.y * 64;
  const int col0 = blockIdx.x * 128;
  const int z = blockIdx.z;
  const int wm = (w >> 1) * 32, wn = (w & 1) * 64;
  const int lcol = l & 15, quad = l >> 4;
  const int sr = l >> 3;
  const int sg = l & 7;
  const bf16* Ag = A + (size_t)row0 * K + (size_t)z * Kh;
  const bf16* Bg = B + (size_t)col0 * K + (size_t)z * Kh;

  f32x4 acc[2][4] = {};

  for (int k0 = 0; k0 < Kh; k0 += 64) {
    __syncthreads();
#pragma unroll
    for (int i = 0; i < 2; ++i) {
      int rb = w * 16 + i * 8;
      int r = rb + sr;
      gload_lds16(Ag + (size_t)r * K + k0 + ((sg ^ (r & 7)) * 8), As + rb * 64);
    }
#pragma unroll
    for (int i = 0; i < 4; ++i) {
      int rb = w * 32 + i * 8;
      int r = rb + sr;
      gload_lds16(Bg + (size_t)r * K + k0 + ((sg ^ (r & 7)) * 8), Bs + rb * 64);
    }
    __syncthreads();
#pragma unroll
    for (int ks = 0; ks < 2; ++ks) {
      bf16x8 af[2], bff[4];
#pragma unroll
      for (int mi = 0; mi < 2; ++mi) {
        int R = wm + mi * 16 + lcol;
        af[mi] = *(const bf16x8*)(As + R * 64 + (((ks * 4 + quad) ^ (R & 7)) * 8));
      }
#pragma unroll
      for (int ni = 0; ni < 4; ++ni) {
        int R = wn + ni * 16 + lcol;
        bff[ni] = *(const bf16x8*)(Bs + R * 64 + (((ks * 4 + quad) ^ (R & 7)) * 8));
      }
#pragma unroll
      for (int mi = 0; mi < 2; ++mi)
#pragma unroll
        for (int ni = 0; ni < 4; ++ni)
          acc[mi][ni] = __builtin_amdgcn_mfma_f32_16x16x32_bf16(
              af[mi], bff[ni], acc[mi][ni], 0, 0, 0);
    }
  }
  float* Cp = C + (size_t)z * part_stride;
#pragma unroll
  for (int mi = 0; mi < 2; ++mi) {
#pragma unroll
    for (int ni = 0; ni < 4; ++ni) {
      int col = col0 + wn + ni * 16 + lcol;
#pragma unroll
      for (int r = 0; r < 4; ++r) {
        int row = row0 + wm + mi * 16 + quad * 4 + r;
        Cp[(size_t)row * N + col] = acc[mi][ni][r] * rs[row];
      }
    }
  }
}

// ---------------------------------------------------------------------------
// 3b) bf16 MFMA GEMM, 64x64 tile, full K, writes fp32 directly (no split-K)
// ---------------------------------------------------------------------------
__global__ __launch_bounds__(256) void gemm_bt64(
    const bf16* __restrict__ A, const bf16* __restrict__ B,
    const float* __restrict__ rs, float* __restrict__ C, int N, int K) {
  __shared__ bf16 As[64 * 64];
  __shared__ bf16 Bs[64 * 64];
  const int tid = threadIdx.x;
  const int w = tid >> 6, l = tid & 63;
  const int row0 = blockIdx.y * 64;
  const int col0 = blockIdx.x * 64;
  const int wm = (w >> 1) * 32, wn = (w & 1) * 32;
  const int lcol = l & 15, quad = l >> 4;
  const int sr = l >> 3;
  const int sg = l & 7;
  const bf16* Ag = A + (size_t)row0 * K;
  const bf16* Bg = B + (size_t)col0 * K;

  f32x4 acc[2][2] = {};

  for (int k0 = 0; k0 < K; k0 += 64) {
    __syncthreads();
#pragma unroll
    for (int i = 0; i < 2; ++i) {
      int rb = w * 16 + i * 8;
      int r = rb + sr;
      gload_lds16(Ag + (size_t)r * K + k0 + ((sg ^ (r & 7)) * 8), As + rb * 64);
    }
#pragma unroll
    for (int i = 0; i < 2; ++i) {
      int rb = w * 16 + i * 8;
      int r = rb + sr;
      gload_lds16(Bg + (size_t)r * K + k0 + ((sg ^ (r & 7)) * 8), Bs + rb * 64);
    }
    __syncthreads();
#pragma unroll
    for (int ks = 0; ks < 2; ++ks) {
      bf16x8 af[2], bff[2];
#pragma unroll
      for (int mi = 0; mi < 2; ++mi) {
        int R = wm + mi * 16 + lcol;
        af[mi] = *(const bf16x8*)(As + R * 64 + (((ks * 4 + quad) ^ (R & 7)) * 8));
      }
#pragma unroll
      for (int ni = 0; ni < 2; ++ni) {
        int R = wn + ni * 16 + lcol;
        bff[ni] = *(const bf16x8*)(Bs + R * 64 + (((ks * 4 + quad) ^ (R & 7)) * 8));
      }
#pragma unroll
      for (int mi = 0; mi < 2; ++mi)
#pragma unroll
        for (int ni = 0; ni < 2; ++ni)
          acc[mi][ni] = __builtin_amdgcn_mfma_f32_16x16x32_bf16(
              af[mi], bff[ni], acc[mi][ni], 0, 0, 0);
    }
  }
#pragma unroll
  for (int mi = 0; mi < 2; ++mi) {
#pragma unroll
    for (int ni = 0; ni < 2; ++ni) {
      int col = col0 + wn + ni * 16 + lcol;
#pragma unroll
      for (int r = 0; r < 4; ++r) {
        int row = row0 + wm + mi * 16 + quad * 4 + r;
        C[(size_t)row * N + col] = acc[mi][ni][r] * rs[row];
      }
    }
  }
}

// ---------------------------------------------------------------------------
// 4a) q/k postprocess: sum split-K partials + rmsnorm + rope; bf16 out.
// ---------------------------------------------------------------------------
__global__ void qk_post(const float* __restrict__ qkvA, const float* __restrict__ qkvB,
                        const float* __restrict__ qw, const float* __restrict__ kw,
                        bf16* __restrict__ Qo, bf16* __restrict__ Ko) {
  const int t = blockIdx.x, h = blockIdx.y, i = threadIdx.x;
  const size_t off = (h < NH)
      ? (size_t)t * QKV_OUT + h * HD
      : (size_t)t * QKV_OUT + 2560 + (h - NH) * HD;
  const float* s1 = qkvA + off;
  const float* s2 = qkvB + off;
  float x0 = s1[2 * i] + s2[2 * i];
  float x1 = s1[2 * i + 1] + s2[2 * i + 1];
  float ss = x0 * x0 + x1 * x1;
  for (int off2 = 1; off2 < 64; off2 <<= 1) ss += __shfl_xor(ss, off2);
  float r = rsqrtf(ss * (1.f / 128.f) + 1e-5f);
  const float* wv = (h < NH) ? qw : kw;
  float y0 = x0 * r * wv[2 * i];
  float y1 = x1 * r * wv[2 * i + 1];
  float inv_freq = powf(500000.f, -(float)(2 * i) * (1.f / 128.f));
  float ang = (float)t * inv_freq;
  float sn, cs;
  sincosf(ang, &sn, &cs);
  float o0 = y0 * cs - y1 * sn;
  float o1 = y0 * sn + y1 * cs;
  if (h < NH) {
    bf16* dst = Qo + ((size_t)t * NH + h) * HD + 2 * i;
    dst[0] = (bf16)o0; dst[1] = (bf16)o1;
  } else {
    bf16* dst = Ko + ((size_t)(h - NH) * SEQ + t) * HD + 2 * i;
    dst[0] = (bf16)o0; dst[1] = (bf16)o1;
  }
}

// ---------------------------------------------------------------------------
// 4b) V transpose: sum partials, fp32 [t][3200+g*128+d] -> Vt bf16 [g][d][t]
// ---------------------------------------------------------------------------
__global__ __launch_bounds__(256) void v_post(const float* __restrict__ qkvA,
                                              const float* __restrict__ qkvB,
                                              bf16* __restrict__ Vt) {
  const int t0 = blockIdx.x * 64, g = blockIdx.y;
  const int tid = threadIdx.x;
  __shared__ bf16 Ls[64 * 137];
  {
    const int tl = tid >> 4;
    const int d0 = (tid & 15) * 8;
#pragma unroll
    for (int pass = 0; pass < 4; ++pass) {
      int t = pass * 16 + tl;
      size_t off = (size_t)(t0 + t) * QKV_OUT + 3200 + g * HD + d0;
      float4 a = *(const float4*)(qkvA + off);
      float4 b = *(const float4*)(qkvA + off + 4);
      float4 a2 = *(const float4*)(qkvB + off);
      float4 b2 = *(const float4*)(qkvB + off + 4);
      bf16* dst = Ls + t * 137 + d0;
      dst[0] = (bf16)(a.x + a2.x); dst[1] = (bf16)(a.y + a2.y);
      dst[2] = (bf16)(a.z + a2.z); dst[3] = (bf16)(a.w + a2.w);
      dst[4] = (bf16)(b.x + b2.x); dst[5] = (bf16)(b.y + b2.y);
      dst[6] = (bf16)(b.z + b2.z); dst[7] = (bf16)(b.w + b2.w);
    }
  }
  __syncthreads();
  {
    const int dl = tid >> 3;
    const int tl0 = (tid & 7) * 8;
#pragma unroll
    for (int pass = 0; pass < 4; ++pass) {
      int d = pass * 32 + dl;
      bf16x8 v;
#pragma unroll
      for (int j = 0; j < 8; ++j) v[j] = Ls[(tl0 + j) * 137 + d];
      *(bf16x8*)(Vt + ((size_t)g * HD + d) * SEQ + t0 + tl0) = v;
    }
  }
}

// ---------------------------------------------------------------------------
// 5) MFMA GQA causal flash attention.
//    Block = 256 thr (4 waves) per (32-q band, head-PAIR of same KV group):
//    waves 0,1 -> head A bands 0,1; waves 2,3 -> head B. K/V staged ONCE per
//    block into double-buffered XOR-swizzled LDS; ONE barrier per tile —
//    stage(kt+1) issued right after it, latency hidden under compute(kt).
//    Output bf16.
// ---------------------------------------------------------------------------
__global__ __launch_bounds__(256) void attn_mfma(
    const bf16* __restrict__ Qb, const bf16* __restrict__ Kb,
    const bf16* __restrict__ Vt, bf16* __restrict__ O) {
  const int qb = 31 - (int)blockIdx.x;     // long blocks first
  const int hp = blockIdx.y;
  const int tid = threadIdx.x;
  const int wave = tid >> 6, lane = tid & 63;
  const int H = (hp >> 1) * 4 + (hp & 1) * 2 + (wave >> 1);
  const int g = H >> 2;
  const int qcol = lane & 15, quad = lane >> 4;
  const int q_tok = qb * 32 + (wave & 1) * 16 + qcol;
  const float scale = 0.08838834764831843f;

  __shared__ bf16 Ks[2][64 * 128];   // [key][d], granules swizzled by key&15
  __shared__ bf16 Vs[2][128 * 64];   // [d][key], granules swizzled by d&7

  const bf16* kbase = Kb + (size_t)g * SEQ * HD;
  const bf16* vbase = Vt + (size_t)g * HD * SEQ;

  bf16x8 qf[4];
  {
    const bf16* qp = Qb + ((size_t)q_tok * NH + H) * HD + quad * 8;
#pragma unroll
    for (int kc = 0; kc < 4; ++kc) qf[kc] = *(const bf16x8*)(qp + kc * 32);
  }

  float m_i = -1e30f, l_i = 0.f;
  f32x4 o_acc[8] = {};
  const int kt_max = (qb * 32 + 31) >> 6;

  const int k_r = lane >> 4, k_g = lane & 15;
  const int v_r = lane >> 3, v_g = lane & 7;

#define STAGE(buf, key0)                                                       \
  {                                                                            \
    _Pragma("unroll") for (int p = 0; p < 4; ++p) {                            \
      int r0 = wave * 16 + p * 4;                                              \
      int r = r0 + k_r;                                                        \
      gload_lds16(kbase + (size_t)((key0) + r) * HD + ((k_g ^ (r & 15)) * 8),  \
                  &Ks[buf][r0 * 128]);                                         \
    }                                                                          \
    _Pragma("unroll") for (int p = 0; p < 4; ++p) {                            \
      int r0 = wave * 32 + p * 8;                                              \
      int r = r0 + v_r;                                                        \
      gload_lds16(vbase + (size_t)r * SEQ + (key0) + ((v_g ^ (r & 7)) * 8),    \
                  &Vs[buf][r0 * 64]);                                          \
    }                                                                          \
  }

  STAGE(0, 0)

  for (int kt = 0; kt <= kt_max; ++kt) {
    const int key0 = kt * 64;
    __syncthreads();     // buf[kt&1] staged (per-wave vmcnt drain + barrier);
                         // also: every wave done reading buf[(kt+1)&1]
    if (kt < kt_max) STAGE((kt + 1) & 1, key0 + 64)
    const bf16* Kt = Ks[kt & 1];
    const bf16* Vtile = Vs[kt & 1];

    // ---- S^T = K · Q^T ----
    f32x4 s[4];
#pragma unroll
    for (int mg = 0; mg < 4; ++mg) {
      const int R = mg * 16 + qcol;
      const bf16* krow = Kt + R * 128;
      f32x4 acc = {0.f, 0.f, 0.f, 0.f};
#pragma unroll
      for (int kc = 0; kc < 4; ++kc) {
        int j = kc * 4 + quad;
        bf16x8 kf = *(const bf16x8*)(krow + ((j ^ (R & 15)) * 8));
        acc = __builtin_amdgcn_mfma_f32_16x16x32_bf16(kf, qf[kc], acc, 0, 0, 0);
      }
      s[mg] = acc;
    }

    // ---- scale + causal mask + online softmax ----
    float mt = -1e30f;
#pragma unroll
    for (int mg = 0; mg < 4; ++mg)
#pragma unroll
      for (int r = 0; r < 4; ++r) {
        int key = key0 + mg * 16 + quad * 4 + r;
        float v = (key <= q_tok) ? s[mg][r] * scale : -1e30f;
        s[mg][r] = v;
        mt = fmaxf(mt, v);
      }
    mt = fmaxf(mt, __shfl_xor(mt, 16));
    mt = fmaxf(mt, __shfl_xor(mt, 32));
    float mnew = fmaxf(m_i, mt);
    float alpha = __expf(m_i - mnew);
    float ps = 0.f;
#pragma unroll
    for (int mg = 0; mg < 4; ++mg)
#pragma unroll
      for (int r = 0; r < 4; ++r) {
        float pv = __expf(s[mg][r] - mnew);
        s[mg][r] = pv;
        ps += pv;
      }
    ps += __shfl_xor(ps, 16);
    ps += __shfl_xor(ps, 32);
    l_i = l_i * alpha + ps;
    m_i = mnew;
#pragma unroll
    for (int mg2 = 0; mg2 < 8; ++mg2)
#pragma unroll
      for (int r = 0; r < 4; ++r) o_acc[mg2][r] *= alpha;

    // ---- P^T B-frags from own regs (key = mg*16 + quad*4 + r) ----
    bf16x8 pb[2];
#pragma unroll
    for (int c = 0; c < 2; ++c)
#pragma unroll
      for (int j = 0; j < 8; ++j)
        pb[c][j] = (bf16)s[c * 2 + (j >> 2)][j & 3];

    // ---- O^T += V^T · P^T ----
#pragma unroll
    for (int mg2 = 0; mg2 < 8; ++mg2) {
      const int R = mg2 * 16 + qcol;
      const bf16* vrow = Vtile + R * 64;
      f32x4 acc = o_acc[mg2];
#pragma unroll
      for (int c = 0; c < 2; ++c) {
        int g8a = c * 8 + quad;
        int g8b = c * 8 + 4 + quad;
        bf16x4 v0 = *(const bf16x4*)(vrow + ((g8a >> 1) ^ (R & 7)) * 8 + (g8a & 1) * 4);
        bf16x4 v1 = *(const bf16x4*)(vrow + ((g8b >> 1) ^ (R & 7)) * 8 + (g8b & 1) * 4);
        bf16x8 vfr;
#pragma unroll
        for (int j = 0; j < 4; ++j) { vfr[j] = v0[j]; vfr[j + 4] = v1[j]; }
        acc = __builtin_amdgcn_mfma_f32_16x16x32_bf16(vfr, pb[c], acc, 0, 0, 0);
      }
      o_acc[mg2] = acc;
    }
  }
#undef STAGE

  const float inv = 1.f / l_i;
  bf16* op = O + (size_t)q_tok * DIM + H * HD + quad * 4;
#pragma unroll
  for (int mg2 = 0; mg2 < 8; ++mg2) {
    bf16x4 vv;
    vv[0] = (bf16)(o_acc[mg2][0] * inv);
    vv[1] = (bf16)(o_acc[mg2][1] * inv);
    vv[2] = (bf16)(o_acc[mg2][2] * inv);
    vv[3] = (bf16)(o_acc[mg2][3] * inv);
    *(bf16x4*)(op + mg2 * 16) = vv;
  }
}

// ---------------------------------------------------------------------------
extern "C" void kernel_launch(void* const* d_in, const int* in_sizes, int n_in,
                              void* d_out, int out_size, void* d_ws, size_t ws_size,
                              hipStream_t stream) {
  const float* x      = (const float*)d_in[0];
  const float* w_qkv  = (const float*)d_in[1];
  const float* ws_qkv = (const float*)d_in[2];
  const float* w_o    = (const float*)d_in[3];
  const float* ws_o   = (const float*)d_in[4];
  const float* qnw    = (const float*)d_in[5];
  const float* knw    = (const float*)d_in[6];
  float* out = (float*)d_out;

  char* p = (char*)d_ws;
  bf16*  act1 = (bf16*)p;  p += (size_t)SEQ * DIM * 2;
  float* rs1  = (float*)p; p += 4096;
  bf16*  wqdq = (bf16*)p;  p += (size_t)QKV_OUT * DIM * 2;
  bf16*  wodq = (bf16*)p;  p += (size_t)DIM * DIM * 2;
  float* qkvA = (float*)p; p += (size_t)SEQ * QKV_OUT * 4;
  float* qkvB = (float*)p; p += (size_t)SEQ * QKV_OUT * 4;
  bf16*  Qb   = (bf16*)p;  p += (size_t)SEQ * NH * HD * 2;
  bf16*  Kb   = (bf16*)p;  p += (size_t)NKV * SEQ * HD * 2;
  bf16*  Vt   = (bf16*)p;  p += (size_t)NKV * HD * SEQ * 2;
  bf16*  attn = (bf16*)p;  p += (size_t)SEQ * DIM * 2;
  bf16*  act2 = (bf16*)p;  p += (size_t)SEQ * DIM * 2;
  float* rs2  = (float*)p; p += 4096;

  quant_kernel<float><<<SEQ, 256, 0, stream>>>(x, act1, rs1, DIM);
  {
    long n1_4 = (long)QKV_OUT * DIM / 4;
    long total4 = n1_4 + (long)DIM * DIM / 4;
    dequant2_kernel<<<(int)((total4 + 255) / 256), 256, 0, stream>>>(
        w_qkv, ws_qkv, wqdq, w_o, ws_o, wodq, n1_4, total4);
  }
  gemm_bt<<<dim3(QKV_OUT / 128, SEQ / 64, 2), 256, 0, stream>>>(
      act1, wqdq, rs1, qkvA, QKV_OUT, DIM, DIM / 2, (size_t)SEQ * QKV_OUT);
  qk_post<<<dim3(SEQ, 25), 64, 0, stream>>>(qkvA, qkvB, qnw, knw, Qb, Kb);
  v_post<<<dim3(SEQ / 64, NKV), 256, 0, stream>>>(qkvA, qkvB, Vt);
  attn_mfma<<<dim3(32, 10), 256, 0, stream>>>(Qb, Kb, Vt, attn);
  quant_kernel<bf16><<<SEQ, 256, 0, stream>>>(attn, act2, rs2, DIM);
  gemm_bt64<<<dim3(DIM / 64, SEQ / 64), 256, 0, stream>>>(
      act2, wodq, rs2, out, DIM, DIM);
}